// Round 6
// baseline (385.180 us; speedup 1.0000x reference)
//
#include <hip/hip_runtime.h>
#include <hip/hip_bf16.h>
#include <cstdint>

typedef __bf16 bf16;
typedef __bf16 bf16x8 __attribute__((ext_vector_type(8)));
typedef __bf16 bf16x4 __attribute__((ext_vector_type(4)));
typedef float floatx4 __attribute__((ext_vector_type(4)));

#define MFMA16(a, b, c) __builtin_amdgcn_mfma_f32_16x16x32_bf16(a, b, c, 0, 0, 0)

__device__ __forceinline__ void gload_lds16(const void* g, void* l) {
    __builtin_amdgcn_global_load_lds(
        (const __attribute__((address_space(1))) void*)g,
        (__attribute__((address_space(3))) void*)l, 16, 0, 0);
}

// ---------------------------------------------------------------------------
// fp32 -> bf16 flat downcast
// ---------------------------------------------------------------------------
__global__ void downcast_kernel(const float* __restrict__ in, bf16* __restrict__ out,
                                size_t n) {
    const size_t i = ((size_t)blockIdx.x * blockDim.x + threadIdx.x) * 4;
    if (i >= n) return;
    const float4 v = *(const float4*)(in + i);
    bf16x4 o = {(bf16)v.x, (bf16)v.y, (bf16)v.z, (bf16)v.w};
    *(bf16x4*)(out + i) = o;
}

// ---------------------------------------------------------------------------
// Transpose + downcast: in fp32 [R][C] -> out bf16 [C][R]
// ---------------------------------------------------------------------------
__global__ void transpose_kernel(const float* __restrict__ in, bf16* __restrict__ out,
                                 int R, int C) {
    __shared__ float tile[32][33];
    const int c0 = blockIdx.x * 32, r0 = blockIdx.y * 32;
    const int tx = threadIdx.x & 31, ty = threadIdx.x >> 5;
    for (int i = 0; i < 32; i += 8)
        tile[ty + i][tx] = in[(size_t)(r0 + ty + i) * C + (c0 + tx)];
    __syncthreads();
    for (int i = 0; i < 32; i += 8)
        out[(size_t)(c0 + ty + i) * R + (r0 + tx)] = (bf16)tile[tx][ty + i];
}

// ---------------------------------------------------------------------------
// GEMM: C[M][N] = A[M][K] @ BT[N][K]^T   (bf16 in, fp32 accum)  [unchanged R5]
// BK=64, XOR-swizzled LDS (seg = sp ^ (row&7)), frag reads 2-way (free).
// ---------------------------------------------------------------------------
template <int MODE>
__global__ __launch_bounds__(256) void gemm_bt_kernel(
    const bf16* __restrict__ A, const bf16* __restrict__ BT,
    int M, int N, int K,
    bf16* __restrict__ qt, bf16* __restrict__ kt, bf16* __restrict__ vt,
    float* __restrict__ Cout) {
    __shared__ alignas(16) bf16 As[128 * 64];
    __shared__ alignas(16) bf16 Bs[128 * 64];

    const int tid = threadIdx.x;
    const int wave = tid >> 6, lane = tid & 63;
    const int quad = lane >> 4, r16 = lane & 15;
    const int m0 = blockIdx.y * 128, n0 = blockIdx.x * 128;
    const int wm = (wave >> 1) * 64, wn = (wave & 1) * 64;

    int srow[4], soff[4];
#pragma unroll
    for (int j = 0; j < 4; ++j) {
        const int c = tid + j * 256;
        srow[j] = c >> 3;
        soff[j] = ((c & 7) ^ (srow[j] & 7)) * 8;
    }

    floatx4 acc[4][4] = {};

    for (int k0 = 0; k0 < K; k0 += 64) {
        __syncthreads();
#pragma unroll
        for (int j = 0; j < 4; ++j) {
            const int c = tid + j * 256;
            gload_lds16(A + (size_t)(m0 + srow[j]) * K + k0 + soff[j], As + c * 8);
            gload_lds16(BT + (size_t)(n0 + srow[j]) * K + k0 + soff[j], Bs + c * 8);
        }
        __syncthreads();

#pragma unroll
        for (int kc = 0; kc < 2; ++kc) {
            bf16x8 a[4], b[4];
#pragma unroll
            for (int i = 0; i < 4; ++i) {
                const int row = wm + i * 16 + r16;
                const int sp = (4 * kc + quad) ^ (row & 7);
                a[i] = *(const bf16x8*)(As + row * 64 + sp * 8);
            }
#pragma unroll
            for (int j = 0; j < 4; ++j) {
                const int row = wn + j * 16 + r16;
                const int sp = (4 * kc + quad) ^ (row & 7);
                b[j] = *(const bf16x8*)(Bs + row * 64 + sp * 8);
            }
#pragma unroll
            for (int i = 0; i < 4; ++i)
#pragma unroll
                for (int j = 0; j < 4; ++j)
                    acc[i][j] = MFMA16(a[i], b[j], acc[i][j]);
        }
    }

    if (MODE == 0) {
        const int t = n0 >> 11;
        const float qscale = 0.08838834764831845f;  // 128^-0.5
#pragma unroll
        for (int i = 0; i < 4; ++i) {
            const int mbase = m0 + wm + i * 16 + quad * 4;
            const int b_ = mbase >> 11;
            const int s = mbase & 2047;
#pragma unroll
            for (int j = 0; j < 4; ++j) {
                const int n = n0 + wn + j * 16 + r16;
                const int h = (n >> 7) & 15, hd = n & 127;
                const int bh = b_ * 16 + h;
                if (t == 0) {
#pragma unroll
                    for (int r = 0; r < 4; ++r)
                        qt[(size_t)(bh * 2048 + s + r) * 128 + hd] =
                            (bf16)(acc[i][j][r] * qscale);
                } else if (t == 1) {
#pragma unroll
                    for (int r = 0; r < 4; ++r)
                        kt[(size_t)(bh * 2048 + s + r) * 128 + hd] = (bf16)acc[i][j][r];
                } else {
                    bf16x4 pv = {(bf16)acc[i][j][0], (bf16)acc[i][j][1],
                                 (bf16)acc[i][j][2], (bf16)acc[i][j][3]};
                    *(bf16x4*)(vt + (size_t)(bh * 128 + hd) * 2048 + s) = pv;
                }
            }
        }
    } else {
#pragma unroll
        for (int i = 0; i < 4; ++i) {
            const int mbase = m0 + wm + i * 16 + quad * 4;
#pragma unroll
            for (int j = 0; j < 4; ++j) {
                const int n = n0 + wn + j * 16 + r16;
#pragma unroll
                for (int r = 0; r < 4; ++r)
                    Cout[(size_t)(mbase + r) * N + n] = acc[i][j][r];
            }
        }
    }
}

// ---------------------------------------------------------------------------
// Flash attention (causal), no-max softmax, BM=128.
// Grid: (16 q-tiles, 32 bh); t = 15 - blockIdx.x (heavy tiles dispatch first,
// LPT packing). 4 waves x 32 q-rows (2 m-frags/wave): K/V frags register-
// reused across both m-tiles -> LDS reads, barriers, staging all ~halved
// per FLOP vs BM=64. BN=64. Wave-uniform diagonal masking.
// ---------------------------------------------------------------------------
__global__ __launch_bounds__(256) void attn_kernel(
    const bf16* __restrict__ qt, const bf16* __restrict__ kt,
    const bf16* __restrict__ vt, bf16* __restrict__ o) {
    __shared__ alignas(16) bf16 Ks[64 * 128];    // (row, sp): seg = sp ^ (row&15)
    __shared__ alignas(16) bf16 Vts[128 * 64];   // (row, sp): seg = sp ^ (row&7)
    __shared__ alignas(16) bf16 Ps[4][32 * 72];  // per-wave P [row][key], stride 72

    const int tid = threadIdx.x;
    const int wave = tid >> 6, lane = tid & 63;
    const int quad = lane >> 4, r16 = lane & 15;
    const int t = 15 - blockIdx.x, bh = blockIdx.y;
    const int b_ = bh >> 4, h = bh & 15;
    const int q0 = t * 128;
    const int w0 = q0 + wave * 32;  // this wave's first q-row

    // Q A-frags for both m-tiles, held in registers
    bf16x8 aq[2][4];
#pragma unroll
    for (int mi = 0; mi < 2; ++mi) {
        const bf16* qbase = qt + (((size_t)bh * 2048 + w0 + mi * 16 + r16) << 7);
#pragma unroll
        for (int kc = 0; kc < 4; ++kc)
            aq[mi][kc] = *(const bf16x8*)(qbase + kc * 32 + quad * 8);
    }

    floatx4 oacc[2][8] = {};
    float lsum[2][4] = {};

    const int niter = 2 * t + 2;  // keys 0 .. q0+127
    for (int it = 0; it < niter; ++it) {
        const int k0 = it * 64;
        __syncthreads();
#pragma unroll
        for (int j = 0; j < 4; ++j) {
            const int c = tid + j * 256;
            const int row = c >> 4, sp = c & 15, s = sp ^ (row & 15);
            gload_lds16(kt + (((size_t)bh * 2048 + k0 + row) << 7) + s * 8,
                        Ks + c * 8);
        }
#pragma unroll
        for (int j = 0; j < 4; ++j) {
            const int c = tid + j * 256;
            const int row = c >> 3, sp = c & 7, s = sp ^ (row & 7);
            gload_lds16(vt + ((size_t)bh * 128 + row) * 2048 + k0 + s * 8,
                        Vts + c * 8);
        }
        __syncthreads();

        // S = Q @ K^T : 32 q-rows x 64 keys; K-frag reused across m-tiles
        floatx4 sacc[2][4] = {};
#pragma unroll
        for (int nt = 0; nt < 4; ++nt) {
            const int row = nt * 16 + r16;
#pragma unroll
            for (int kc = 0; kc < 4; ++kc) {
                const int sp = (4 * kc + quad) ^ r16;  // row&15 == r16
                bf16x8 bk = *(const bf16x8*)(Ks + row * 128 + sp * 8);
                sacc[0][nt] = MFMA16(aq[0][kc], bk, sacc[0][nt]);
                sacc[1][nt] = MFMA16(aq[1][kc], bk, sacc[1][nt]);
            }
        }

        // exp (no max subtraction); wave-uniform masked path near diagonal
        const bool need_mask = (k0 + 63) > w0;
#pragma unroll
        for (int mi = 0; mi < 2; ++mi) {
            const int qrowC = w0 + mi * 16 + quad * 4;
            if (need_mask) {
#pragma unroll
                for (int nt = 0; nt < 4; ++nt)
#pragma unroll
                    for (int r = 0; r < 4; ++r) {
                        const bool ok = (k0 + nt * 16 + r16) <= (qrowC + r);
                        const float e = ok ? __expf(sacc[mi][nt][r]) : 0.f;
                        lsum[mi][r] += e;
                        Ps[wave][(mi * 16 + quad * 4 + r) * 72 + nt * 16 + r16] =
                            (bf16)e;
                    }
            } else {
#pragma unroll
                for (int nt = 0; nt < 4; ++nt)
#pragma unroll
                    for (int r = 0; r < 4; ++r) {
                        const float e = __expf(sacc[mi][nt][r]);
                        lsum[mi][r] += e;
                        Ps[wave][(mi * 16 + quad * 4 + r) * 72 + nt * 16 + r16] =
                            (bf16)e;
                    }
            }
        }

        // O += P @ V : V-frag reused across m-tiles
#pragma unroll
        for (int kblk = 0; kblk < 2; ++kblk) {
            bf16x8 ap0 = *(const bf16x8*)(&Ps[wave][r16 * 72 + kblk * 32 + quad * 8]);
            bf16x8 ap1 =
                *(const bf16x8*)(&Ps[wave][(16 + r16) * 72 + kblk * 32 + quad * 8]);
#pragma unroll
            for (int nt2 = 0; nt2 < 8; ++nt2) {
                const int row = nt2 * 16 + r16;
                const int sp = (4 * kblk + quad) ^ (row & 7);
                bf16x8 bv = *(const bf16x8*)(Vts + row * 64 + sp * 8);
                oacc[0][nt2] = MFMA16(ap0, bv, oacc[0][nt2]);
                oacc[1][nt2] = MFMA16(ap1, bv, oacc[1][nt2]);
            }
        }
    }

    // l-reduction + normalize + store (coalesced along r16 -> hd)
#pragma unroll
    for (int mi = 0; mi < 2; ++mi)
#pragma unroll
        for (int r = 0; r < 4; ++r) {
            float s = lsum[mi][r];
#pragma unroll
            for (int off = 1; off < 16; off <<= 1) s += __shfl_xor(s, off);
            const float inv = 1.0f / s;
            const int qq = w0 + mi * 16 + quad * 4 + r;
            bf16* orow = o + (size_t)(b_ * 2048 + qq) * 2048 + h * 128;
#pragma unroll
            for (int nt2 = 0; nt2 < 8; ++nt2)
                orow[nt2 * 16 + r16] = (bf16)(oacc[mi][nt2][r] * inv);
        }
}

// ---------------------------------------------------------------------------
extern "C" void kernel_launch(void* const* d_in, const int* in_sizes, int n_in,
                              void* d_out, int out_size, void* d_ws, size_t ws_size,
                              hipStream_t stream) {
    const float* x    = (const float*)d_in[0];  // [4096][2048] fp32
    const float* Wqkv = (const float*)d_in[1];  // [2048][6144] fp32
    const float* Wo   = (const float*)d_in[2];  // [2048][2048] fp32
    float* out        = (float*)d_out;          // [4096][2048] fp32

    char* ws = (char*)d_ws;
    bf16* xb    = (bf16*)ws; ws += (size_t)4096 * 2048 * 2;
    bf16* WqkvT = (bf16*)ws; ws += (size_t)6144 * 2048 * 2;
    bf16* WoT   = (bf16*)ws; ws += (size_t)2048 * 2048 * 2;
    bf16* qt    = (bf16*)ws; ws += (size_t)32 * 2048 * 128 * 2;
    bf16* kt    = (bf16*)ws; ws += (size_t)32 * 2048 * 128 * 2;
    bf16* vt    = (bf16*)ws; ws += (size_t)32 * 128 * 2048 * 2;
    bf16* ob    = (bf16*)ws; ws += (size_t)4096 * 2048 * 2;

    downcast_kernel<<<8192, 256, 0, stream>>>(x, xb, (size_t)4096 * 2048);
    transpose_kernel<<<dim3(192, 64), 256, 0, stream>>>(Wqkv, WqkvT, 2048, 6144);
    transpose_kernel<<<dim3(64, 64), 256, 0, stream>>>(Wo, WoT, 2048, 2048);

    gemm_bt_kernel<0><<<dim3(48, 32), 256, 0, stream>>>(
        xb, WqkvT, 4096, 6144, 2048, qt, kt, vt, nullptr);

    attn_kernel<<<dim3(16, 32), 256, 0, stream>>>(qt, kt, vt, ob);

    gemm_bt_kernel<1><<<dim3(16, 32), 256, 0, stream>>>(
        ob, WoT, 4096, 2048, 2048, nullptr, nullptr, nullptr, out);
}